// Round 1
// baseline (14.745 us; speedup 1.0000x reference)
//
#include <hip/hip_runtime.h>

#define CLAMP_MIN 1e-12f
#define CLAMP_MAX 1e12f

// Kernel 1: one wave (64 lanes) per sample.
// dist[i] = clamp(||x_i||^2 + ||c_{y_i}||^2 - 2 x_i . c_{y_i})
__global__ void __launch_bounds__(64) center_dist_kernel(
    const float* __restrict__ x,
    const float* __restrict__ centers,
    const int* __restrict__ labels,
    float* __restrict__ dist,
    int feat) {
    const int i = blockIdx.x;
    const int lane = threadIdx.x;  // 0..63

    const float* xr = x + (size_t)i * feat;
    const float* cr = centers + (size_t)labels[i] * feat;

    // feat = 512: 64 lanes x 2 iterations x float4 = 512 floats.
    float part = 0.0f;
    for (int k = lane * 4; k < feat; k += 64 * 4) {
        const float4 xv = *reinterpret_cast<const float4*>(xr + k);
        const float4 cv = *reinterpret_cast<const float4*>(cr + k);
        float sxx = xv.x * xv.x + xv.y * xv.y + xv.z * xv.z + xv.w * xv.w;
        float scc = cv.x * cv.x + cv.y * cv.y + cv.z * cv.z + cv.w * cv.w;
        float sxc = xv.x * cv.x + xv.y * cv.y + xv.z * cv.z + xv.w * cv.w;
        part += sxx + scc - 2.0f * sxc;
    }

    // Wave-64 butterfly-free shuffle-down reduction.
    #pragma unroll
    for (int off = 32; off > 0; off >>= 1) part += __shfl_down(part, off);

    if (lane == 0) {
        float d = fminf(fmaxf(part, CLAMP_MIN), CLAMP_MAX);
        dist[i] = d;
    }
}

// Kernel 2: deterministic single-block mean reduction of n floats.
__global__ void __launch_bounds__(256) mean_reduce_kernel(
    const float* __restrict__ dist,
    float* __restrict__ out,
    int n) {
    __shared__ float smem[4];  // 256 threads = 4 waves
    float s = 0.0f;
    for (int k = threadIdx.x; k < n; k += 256) s += dist[k];

    #pragma unroll
    for (int off = 32; off > 0; off >>= 1) s += __shfl_down(s, off);

    const int wid = threadIdx.x >> 6;
    if ((threadIdx.x & 63) == 0) smem[wid] = s;
    __syncthreads();
    if (threadIdx.x == 0) {
        float t = smem[0] + smem[1] + smem[2] + smem[3];
        out[0] = t / (float)n;
    }
}

extern "C" void kernel_launch(void* const* d_in, const int* in_sizes, int n_in,
                              void* d_out, int out_size, void* d_ws, size_t ws_size,
                              hipStream_t stream) {
    const float* x       = (const float*)d_in[0];
    const float* centers = (const float*)d_in[1];
    const int*   labels  = (const int*)d_in[2];
    float* out = (float*)d_out;

    const int batch = in_sizes[2];             // 4096
    const int feat  = in_sizes[0] / batch;     // 512

    float* dist = (float*)d_ws;                // batch floats of scratch

    center_dist_kernel<<<batch, 64, 0, stream>>>(x, centers, labels, dist, feat);
    mean_reduce_kernel<<<1, 256, 0, stream>>>(dist, out, batch);
}